// Round 11
// baseline (6515.859 us; speedup 1.0000x reference)
//
#include <hip/hip_runtime.h>
#include <math.h>

#define B_ 8
#define N_ 16384
#define M_ 4096
#define D_ 512
#define TPB 1024
#define PPT 16          // N_ / TPB points per thread

#define FEAT_SZ (B_ * M_ * D_)          // 16777216
#define COFF FEAT_SZ                    // coords_out
#define TOFF (FEAT_SZ + 2 * B_ * M_)    // times_out
#define POFF (TOFF + B_ * M_)           // pol_out

#define R16(F) F(0) F(1) F(2) F(3) F(4) F(5) F(6) F(7) \
               F(8) F(9) F(10) F(11) F(12) F(13) F(14) F(15)

// DPP row ctrl: row_shr:n = 0x110|n, row_bcast15 = 0x142, row_bcast31 = 0x143.
template <int CTRL>
__device__ __forceinline__ float dpp_max_step(float x) {
    const int y = __builtin_amdgcn_update_dpp(0, __float_as_int(x),
                                              CTRL, 0xf, 0xf, true);
    return fmaxf(x, __int_as_float(y));   // invalid lanes read 0; s values > 0
}

__device__ __forceinline__ unsigned spread4(unsigned v) {
    return (v & 1u) | ((v & 2u) << 2) | ((v & 4u) << 4) | ((v & 8u) << 6);
}
__device__ __forceinline__ unsigned mcode(float x, float y, float tt) {
    unsigned mx = min((unsigned)(int)(x * 16.0f), 15u);
    unsigned my = min((unsigned)(int)(y * 16.0f), 15u);
    unsigned mt = min((unsigned)(int)(tt * 16.0f), 15u);
    return spread4(mx) | (spread4(my) << 1) | (spread4(mt) << 2);   // 12-bit Morton
}

// ---------------------------------------------------------------------------
// Kernel 0: Morton counting-sort (per batch). Stages sorted (x,y,t,origid)
// into global ws so fps threads own spatially-contiguous point groups.
// Order within a bucket is nondeterministic (atomic scatter) — harmless:
// skips are exact and argmax ties break on orig id, so OUTPUT is deterministic.
// ---------------------------------------------------------------------------
__global__ __launch_bounds__(TPB) void msort_kernel(
    const float* __restrict__ coords, const float* __restrict__ times,
    float* __restrict__ sortx, float* __restrict__ sorty,
    float* __restrict__ sortt, unsigned* __restrict__ sortid)
{
    const int b = blockIdx.x, t = threadIdx.x;
    const float* cb = coords + (size_t)b * N_ * 2;
    const float* tb = times + (size_t)b * N_;
    const size_t bo = (size_t)b * N_;

    __shared__ unsigned cnt[4096];
    __shared__ unsigned wsum[TPB];

    for (int i = t; i < 4096; i += TPB) cnt[i] = 0;
    __syncthreads();

    for (int j = 0; j < PPT; ++j) {                 // count
        const int gi = j * TPB + t;
        const float2 c2 = *(const float2*)(cb + 2 * (size_t)gi);
        atomicAdd(&cnt[mcode(c2.x, c2.y, tb[gi])], 1u);
    }
    __syncthreads();

    {   // exclusive prefix sum over 4096 (4 per thread + serial 1024 scan)
        const unsigned c0 = cnt[4 * t], c1 = cnt[4 * t + 1],
                       c2 = cnt[4 * t + 2], c3 = cnt[4 * t + 3];
        wsum[t] = c0 + c1 + c2 + c3;
        __syncthreads();
        if (t == 0) {
            unsigned run = 0;
            for (int i = 0; i < TPB; ++i) { unsigned v = wsum[i]; wsum[i] = run; run += v; }
        }
        __syncthreads();
        const unsigned base = wsum[t];
        cnt[4 * t] = base;
        cnt[4 * t + 1] = base + c0;
        cnt[4 * t + 2] = base + c0 + c1;
        cnt[4 * t + 3] = base + c0 + c1 + c2;
    }
    __syncthreads();

    for (int j = 0; j < PPT; ++j) {                 // scatter
        const int gi = j * TPB + t;
        const float2 c2 = *(const float2*)(cb + 2 * (size_t)gi);
        const float tt = tb[gi];
        const unsigned pos = atomicAdd(&cnt[mcode(c2.x, c2.y, tt)], 1u);
        sortx[bo + pos] = c2.x;
        sorty[bo + pos] = c2.y;
        sortt[bo + pos] = tt;
        sortid[bo + pos] = (unsigned)gi;
    }
}

// ---------------------------------------------------------------------------
// Kernel 1: farthest point sampling with EXACT bbox pruning.
//
// Bit-exact chain (verified r2-r10): d2 = fma(dz,dz, fma(dx,dx, dy*dy));
// s = sqrt_rn(fadd_rn(d2,1e-8)); min in d2 domain; s-domain argmax with
// first-ORIG-index tie-break + sqrt-collapse ulp-window fixup.
//
// Pruning: thread owns 16 Morton-contiguous sorted points; keeps bbox (6 regs)
// + TM = max_i m_i. Skip all updates when lb2(center,bbox)*(1-4e-6) >= TM:
// then d2_f(p_i,c) >= lb2_f*(1-2e-6) > TM >= m_i for all i, so every fminf is
// a provable no-op — EXACT skip, no staleness. Morton order clusters the
// ~N/k affected threads into 1-2 waves -> most waves run only the ~60-inst
// fast path instead of 16 LDS reads + 128 VALU (r10's measured floor).
//
// Publish: dual LDS atomicMin keyed (origid<<32 | payload): payloads sortedpos
// and t_bits; unique min origid wins both -> consistent. lx,ly from strided
// LDS cxy[sortedpos]; lt from key. idx_out gets ORIG ids as before.
// ---------------------------------------------------------------------------
__global__ __launch_bounds__(TPB)
__attribute__((amdgpu_waves_per_eu(4, 4)))
void fps_kernel(
    const float* __restrict__ coords, const float* __restrict__ times,
    const float* __restrict__ sortx, const float* __restrict__ sorty,
    const float* __restrict__ sortt, const unsigned* __restrict__ sortid,
    int* __restrict__ idx_out)
{
    const int b = blockIdx.x;
    const int t = threadIdx.x;
    const float* cb = coords + (size_t)b * N_ * 2;
    const float* tb = times + (size_t)b * N_;
    const size_t bo = (size_t)b * N_;

    __shared__ float2 cxy[N_];          // sorted pos p at [(p&15)*TPB + (p>>4)]
    __shared__ __align__(16) float red_s[16];
    __shared__ unsigned long long nxt_pos[2], nxt_t[2];

#define DECLV(i) float pt##i, m##i;
    R16(DECLV)
#undef DECLV
    unsigned id2_0, id2_1, id2_2, id2_3, id2_4, id2_5, id2_6, id2_7;

    float bx0 = 1e30f, bx1 = -1e30f, by0 = 1e30f, by1 = -1e30f,
          bt0 = 1e30f, bt1 = -1e30f;

#define LOADV(i) { const int p = t * PPT + (i);                               \
        const float x = sortx[bo + p], y = sorty[bo + p], tt = sortt[bo + p]; \
        float2 v2; v2.x = x; v2.y = y;                                        \
        cxy[(i) * TPB + t] = v2;                                              \
        pt##i = tt; m##i = INFINITY;                                          \
        bx0 = fminf(bx0, x); bx1 = fmaxf(bx1, x);                             \
        by0 = fminf(by0, y); by1 = fmaxf(by1, y);                             \
        bt0 = fminf(bt0, tt); bt1 = fmaxf(bt1, tt); }
    R16(LOADV)
#undef LOADV

#define LOADID(r) id2_##r = (sortid[bo + t * PPT + 2 * (r)] & 0xffffu) |      \
                            (sortid[bo + t * PPT + 2 * (r) + 1] << 16);
    LOADID(0) LOADID(1) LOADID(2) LOADID(3)
    LOADID(4) LOADID(5) LOADID(6) LOADID(7)
#undef LOADID

#define PINV(i) asm("" : "+v"(pt##i));
    R16(PINV)
#undef PINV
    asm("" : "+v"(id2_0), "+v"(id2_1), "+v"(id2_2), "+v"(id2_3));
    asm("" : "+v"(id2_4), "+v"(id2_5), "+v"(id2_6), "+v"(id2_7));

    if (t == 0) {
        idx_out[b * M_] = 0;                        // deterministic seed
        nxt_pos[0] = nxt_pos[1] = ~0ull;
        nxt_t[0] = nxt_t[1] = ~0ull;
    }
    float lx = cb[0], ly = cb[1], lt = tb[0];
    float TM = INFINITY;
    __syncthreads();

    const int wave = t >> 6;
    const int lane = t & 63;

    for (int k = 1; k < M_; ++k) {
        const int par = k & 1;

        // ---- exact bbox skip test
        const float ddx = fmaxf(fmaxf(bx0 - lx, lx - bx1), 0.0f);
        const float ddy = fmaxf(fmaxf(by0 - ly, ly - by1), 0.0f);
        const float ddt = fmaxf(fmaxf(bt0 - lt, lt - bt1), 0.0f);
        const float lb2 = __fmaf_rn(ddt, ddt,
                          __fmaf_rn(ddx, ddx, __fmul_rn(ddy, ddy)));

        if (!(lb2 * 0.999996f >= TM)) {
            // update path (rare after early iterations)
#define UPDV(i) { const float2 c2 = cxy[(i) * TPB + t];                       \
            const float dx = c2.x - lx;                                       \
            const float dy = c2.y - ly;                                       \
            const float dz = pt##i - lt;                                      \
            const float d2 = __fmaf_rn(dz, dz, __fmaf_rn(dx, dx,              \
                                                     __fmul_rn(dy, dy)));     \
            m##i = fminf(m##i, d2); }
            R16(UPDV)
#undef UPDV
            const float a0 = fmaxf(fmaxf(m0, m1), m2);
            const float a1 = fmaxf(fmaxf(m3, m4), m5);
            const float a2 = fmaxf(fmaxf(m6, m7), m8);
            const float a3 = fmaxf(fmaxf(m9, m10), m11);
            const float a4 = fmaxf(fmaxf(m12, m13), m14);
            TM = fmaxf(fmaxf(fmaxf(a0, a1), a2), fmaxf(fmaxf(a3, a4), m15));
        }

        const float s_local = __fsqrt_rn(__fadd_rn(TM, 1e-8f));

        // DPP wave-max: lane 63 ends with the wave max
        float v = s_local;
        v = dpp_max_step<0x111>(v);   // row_shr:1
        v = dpp_max_step<0x112>(v);   // row_shr:2
        v = dpp_max_step<0x114>(v);   // row_shr:4
        v = dpp_max_step<0x118>(v);   // row_shr:8
        v = dpp_max_step<0x142>(v);   // row_bcast:15
        v = dpp_max_step<0x143>(v);   // row_bcast:31
        if (lane == 63) red_s[wave] = v;
        __syncthreads();                              // bar1

        if (t == 0) { nxt_pos[par ^ 1] = ~0ull; nxt_t[par ^ 1] = ~0ull; }

        const float4* rp = (const float4*)red_s;
        const float4 r0 = rp[0], r1 = rp[1], r2 = rp[2], r3 = rp[3];
        const float s_star = fmaxf(
            fmaxf(fmaxf(fmaxf(r0.x, r0.y), fmaxf(r0.z, r0.w)),
                  fmaxf(fmaxf(r1.x, r1.y), fmaxf(r1.z, r1.w))),
            fmaxf(fmaxf(fmaxf(r2.x, r2.y), fmaxf(r2.z, r2.w)),
                  fmaxf(fmaxf(r3.x, r3.y), fmaxf(r3.z, r3.w))));

        // ---- winner path
        if (s_local == s_star) {
            const float bm = TM;
            unsigned bid = 0xffffffffu; unsigned bpos = 0; float bt_ = 0.0f;

#define SEL1(j, reg, sh) if (m##j == bm) {                                    \
            const unsigned idj = ((reg) >> (sh)) & 0xffffu;                   \
            if (idj < bid) { bid = idj; bpos = (unsigned)(t * PPT + (j));     \
                             bt_ = pt##j; } }
            SEL1(0, id2_0, 0)  SEL1(1, id2_0, 16)
            SEL1(2, id2_1, 0)  SEL1(3, id2_1, 16)
            SEL1(4, id2_2, 0)  SEL1(5, id2_2, 16)
            SEL1(6, id2_3, 0)  SEL1(7, id2_3, 16)
            SEL1(8, id2_4, 0)  SEL1(9, id2_4, 16)
            SEL1(10, id2_5, 0) SEL1(11, id2_5, 16)
            SEL1(12, id2_6, 0) SEL1(13, id2_6, 16)
            SEL1(14, id2_7, 0) SEL1(15, id2_7, 16)
#undef SEL1

            const unsigned bmu = __float_as_uint(bm);
            const float thresh = __uint_as_float(bmu >= 32u ? bmu - 32u : 0u);
            float cntw = 0.0f;
#define CNTV(i) cntw += (m##i >= thresh) ? 1.0f : 0.0f;
            R16(CNTV)
#undef CNTV
            if (cntw > 1.5f) {     // rare: sqrt-collapse ties — re-select
                bid = 0xffffffffu; bpos = 0; bt_ = 0.0f;
#define FIX1(j, reg, sh) if (m##j >= thresh) {                                \
                const float sj = __fsqrt_rn(__fadd_rn(m##j, 1e-8f));          \
                if (sj == s_local) {                                          \
                    const unsigned idj = ((reg) >> (sh)) & 0xffffu;           \
                    if (idj < bid) { bid = idj;                               \
                        bpos = (unsigned)(t * PPT + (j)); bt_ = pt##j; } } }
                FIX1(0, id2_0, 0)  FIX1(1, id2_0, 16)
                FIX1(2, id2_1, 0)  FIX1(3, id2_1, 16)
                FIX1(4, id2_2, 0)  FIX1(5, id2_2, 16)
                FIX1(6, id2_3, 0)  FIX1(7, id2_3, 16)
                FIX1(8, id2_4, 0)  FIX1(9, id2_4, 16)
                FIX1(10, id2_5, 0) FIX1(11, id2_5, 16)
                FIX1(12, id2_6, 0) FIX1(13, id2_6, 16)
                FIX1(14, id2_7, 0) FIX1(15, id2_7, 16)
#undef FIX1
            }
            const unsigned long long hi = ((unsigned long long)bid) << 32;
            atomicMin(&nxt_pos[par], hi | bpos);
            atomicMin(&nxt_t[par], hi | __float_as_uint(bt_));
        }
        __syncthreads();                              // bar2

        const unsigned long long kp = nxt_pos[par];
        const unsigned long long kt = nxt_t[par];
        const int gi = (int)(kp >> 32);
        const unsigned pos = (unsigned)kp;
        lt = __uint_as_float((unsigned)kt);
        const float2 wv = cxy[(pos & 15u) * TPB + (pos >> 4)];  // broadcast
        lx = wv.x; ly = wv.y;
        if (t == 0) idx_out[b * M_ + k] = gi;
    }
}

// ---------------------------------------------------------------------------
// Kernel 2: gather coords/times/polarities at sampled indices.
// ---------------------------------------------------------------------------
__global__ __launch_bounds__(256) void gather_kernel(
    const float* __restrict__ coords, const float* __restrict__ times,
    const float* __restrict__ pol, const int* __restrict__ idx,
    float* __restrict__ out)
{
    int i = blockIdx.x * 256 + threadIdx.x;       // 0 .. B_*M_-1
    if (i >= B_ * M_) return;
    int b = i >> 12;                              // / M_
    int g = b * N_ + idx[i];
    float2 c2 = *(const float2*)(coords + 2 * (size_t)g);
    *(float2*)(out + COFF + 2 * (size_t)i) = c2;
    out[TOFF + i] = times[g];
    out[POFF + i] = pol[g];
}

// ---------------------------------------------------------------------------
// Kernel 3: gathered GEMM + bias.  C[row, o] = features[src(row), :] . W[o, :]
// ---------------------------------------------------------------------------
#define BM 32
#define BN 128
#define BK 32

__global__ __launch_bounds__(256) void proj_kernel(
    const float* __restrict__ features, const float* __restrict__ W,
    const float* __restrict__ bias, const int* __restrict__ idx,
    float* __restrict__ out)
{
    __shared__ float a_lds[BK][BM + 4];
    __shared__ float w_lds[BK][BN];
    __shared__ int   src[BM];

    const int t = threadIdx.x;
    const int rowBase = blockIdx.x * BM;
    const int oBase = blockIdx.y * BN;

    if (t < BM) {
        int row = rowBase + t;
        int b = row >> 12;                // / M_
        src[t] = b * N_ + idx[row];
    }
    __syncthreads();

    const int rt = t >> 5;
    const int ot = t & 31;
    const int lr = t >> 3;
    const int lk = (t & 7) * 4;

    float c[4][4] = {};

    for (int kc = 0; kc < D_; kc += BK) {
        {
            float4 v = *(const float4*)(features + (size_t)src[lr] * D_ + kc + lk);
            a_lds[lk + 0][lr] = v.x; a_lds[lk + 1][lr] = v.y;
            a_lds[lk + 2][lr] = v.z; a_lds[lk + 3][lr] = v.w;
        }
#pragma unroll
        for (int p = 0; p < 4; ++p) {
            int o = p * 32 + lr;
            float4 v = *(const float4*)(W + (size_t)(oBase + o) * D_ + kc + lk);
            w_lds[lk + 0][o] = v.x; w_lds[lk + 1][o] = v.y;
            w_lds[lk + 2][o] = v.z; w_lds[lk + 3][o] = v.w;
        }
        __syncthreads();

#pragma unroll
        for (int k = 0; k < BK; ++k) {
            float4 af = *(const float4*)&a_lds[k][rt * 4];
            float4 wf = *(const float4*)&w_lds[k][ot * 4];
            float av[4] = { af.x, af.y, af.z, af.w };
            float wv[4] = { wf.x, wf.y, wf.z, wf.w };
#pragma unroll
            for (int ri = 0; ri < 4; ++ri)
#pragma unroll
                for (int oi = 0; oi < 4; ++oi)
                    c[ri][oi] = fmaf(av[ri], wv[oi], c[ri][oi]);
        }
        __syncthreads();
    }

    float4 bv = *(const float4*)(bias + oBase + ot * 4);
    float bvv[4] = { bv.x, bv.y, bv.z, bv.w };
#pragma unroll
    for (int ri = 0; ri < 4; ++ri) {
        int row = rowBase + rt * 4 + ri;
        float4 o4;
        o4.x = c[ri][0] + bvv[0];
        o4.y = c[ri][1] + bvv[1];
        o4.z = c[ri][2] + bvv[2];
        o4.w = c[ri][3] + bvv[3];
        *(float4*)(out + (size_t)row * D_ + oBase + ot * 4) = o4;
    }
}

// ---------------------------------------------------------------------------
// Kernel 4: LayerNorm in place over the proj output. One wave per row.
// ---------------------------------------------------------------------------
__global__ __launch_bounds__(256) void ln_kernel(
    float* __restrict__ out, const float* __restrict__ gamma,
    const float* __restrict__ beta)
{
    const int w = threadIdx.x >> 6;
    const int lane = threadIdx.x & 63;
    const size_t row = (size_t)blockIdx.x * 4 + w;
    float* p = out + row * D_;

    float4 v0 = *(const float4*)(p + lane * 8);
    float4 v1 = *(const float4*)(p + lane * 8 + 4);
    float x[8] = { v0.x, v0.y, v0.z, v0.w, v1.x, v1.y, v1.z, v1.w };

    float sum = 0.f;
#pragma unroll
    for (int i = 0; i < 8; ++i) sum += x[i];
#pragma unroll
    for (int off = 1; off < 64; off <<= 1) sum += __shfl_xor(sum, off);
    const float mu = sum * (1.0f / 512.0f);

    float sq = 0.f;
#pragma unroll
    for (int i = 0; i < 8; ++i) { float d = x[i] - mu; sq = fmaf(d, d, sq); }
#pragma unroll
    for (int off = 1; off < 64; off <<= 1) sq += __shfl_xor(sq, off);
    const float inv = rsqrtf(sq * (1.0f / 512.0f) + 1e-5f);

    float4 g0 = *(const float4*)(gamma + lane * 8);
    float4 g1 = *(const float4*)(gamma + lane * 8 + 4);
    float4 b0 = *(const float4*)(beta + lane * 8);
    float4 b1 = *(const float4*)(beta + lane * 8 + 4);
    float g[8] = { g0.x, g0.y, g0.z, g0.w, g1.x, g1.y, g1.z, g1.w };
    float be[8] = { b0.x, b0.y, b0.z, b0.w, b1.x, b1.y, b1.z, b1.w };

    float y[8];
#pragma unroll
    for (int i = 0; i < 8; ++i) y[i] = fmaf((x[i] - mu) * inv, g[i], be[i]);

    float4 o0 = { y[0], y[1], y[2], y[3] };
    float4 o1 = { y[4], y[5], y[6], y[7] };
    *(float4*)(p + lane * 8) = o0;
    *(float4*)(p + lane * 8 + 4) = o1;
}

// ---------------------------------------------------------------------------
extern "C" void kernel_launch(void* const* d_in, const int* in_sizes, int n_in,
                              void* d_out, int out_size, void* d_ws, size_t ws_size,
                              hipStream_t stream)
{
    const float* features   = (const float*)d_in[0];
    const float* coords     = (const float*)d_in[1];
    const float* times      = (const float*)d_in[2];
    const float* polarities = (const float*)d_in[3];
    const float* W          = (const float*)d_in[4];
    const float* bias       = (const float*)d_in[5];
    const float* gamma      = (const float*)d_in[6];
    const float* beta       = (const float*)d_in[7];
    float* out = (float*)d_out;

    // ws layout: [0, 128K) idx; then sortx/sorty/sortt/sortid (512K each) = 2.2 MB
    int* idx = (int*)d_ws;
    float* sortx = (float*)((char*)d_ws + (size_t)B_ * M_ * 4);
    float* sorty = sortx + (size_t)B_ * N_;
    float* sortt = sorty + (size_t)B_ * N_;
    unsigned* sortid = (unsigned*)(sortt + (size_t)B_ * N_);

    msort_kernel<<<B_, TPB, 0, stream>>>(coords, times, sortx, sorty, sortt, sortid);

    fps_kernel<<<B_, TPB, 0, stream>>>(coords, times, sortx, sorty, sortt,
                                       sortid, idx);

    gather_kernel<<<(B_ * M_ + 255) / 256, 256, 0, stream>>>(
        coords, times, polarities, idx, out);

    dim3 pgrid(B_ * M_ / BM, D_ / BN);            // (1024, 4)
    proj_kernel<<<pgrid, 256, 0, stream>>>(features, W, bias, idx, out);

    ln_kernel<<<B_ * M_ / 4, 256, 0, stream>>>(out, gamma, beta);
}